// Round 1
// baseline (824.076 us; speedup 1.0000x reference)
//
#include <hip/hip_runtime.h>

typedef unsigned short u16;
using short8 = __attribute__((ext_vector_type(8))) short;
using u16x8  = __attribute__((ext_vector_type(8))) unsigned short;
using f32x4  = __attribute__((ext_vector_type(4))) float;

#define B_   4
#define S_   8192
#define D_   1024
#define H_   8
#define DH_  128
#define NB_  128
#define M_   (B_ * S_)   // 32768

static __device__ __forceinline__ float bf2f(u16 u) {
  union { unsigned int i; float f; } v; v.i = ((unsigned int)u) << 16; return v.f;
}
static __device__ __forceinline__ u16 f2bf(float f) {
  unsigned int x = __float_as_uint(f);
  unsigned int r = (x + 0x7fffu + ((x >> 16) & 1u)) >> 16;
  return (u16)r;
}
static __device__ __forceinline__ f32x4 mfma16(short8 a, short8 b, f32x4 c) {
  return __builtin_amdgcn_mfma_f32_16x16x32_bf16(a, b, c, 0, 0, 0);
}
// async global->LDS, 16B per lane; dest MUST be wave-uniform base + lane*16 (linear)
static __device__ __forceinline__ void gload16(const u16* g, u16* l) {
  __builtin_amdgcn_global_load_lds(
      (const __attribute__((address_space(1))) void*)g,
      (__attribute__((address_space(3))) void*)l, 16, 0, 0);
}

// ---------------- convert f32 -> bf16, 8 elems/thread ----------------
__global__ __launch_bounds__(256) void cvt_k(const float* __restrict__ src,
                                             u16* __restrict__ dst) {
  const size_t i = ((size_t)blockIdx.x * 256 + threadIdx.x) * 8;
  const f32x4 a = *(const f32x4*)(src + i);
  const f32x4 b = *(const f32x4*)(src + i + 4);
  u16x8 r;
  r[0] = f2bf(a[0]); r[1] = f2bf(a[1]); r[2] = f2bf(a[2]); r[3] = f2bf(a[3]);
  r[4] = f2bf(b[0]); r[5] = f2bf(b[1]); r[6] = f2bf(b[2]); r[7] = f2bf(b[3]);
  *(u16x8*)(dst + i) = r;
}

// ---------------- transpose 1024x1024: dst_bf16[n][k] = src_f32[k][n] ----------------
__global__ __launch_bounds__(256) void transpose_k(const float* __restrict__ src,
                                                   u16* __restrict__ dst) {
  __shared__ float tile[32][33];
  const int bx = blockIdx.x * 32, by = blockIdx.y * 32;
  const int tx = threadIdx.x, ty = threadIdx.y;
#pragma unroll
  for (int i = ty; i < 32; i += 8) tile[i][tx] = src[(size_t)(by + i) * D_ + bx + tx];
  __syncthreads();
#pragma unroll
  for (int i = ty; i < 32; i += 8) dst[(size_t)(bx + i) * D_ + by + tx] = f2bf(tile[tx][i]);
}

// ---------------- hash angles: angles[b][h][s] = h0/(h1+eps), exact f32 ----------------
__global__ __launch_bounds__(128) void angles_k(const float* __restrict__ x,
                                                const float* __restrict__ Wh,
                                                float* __restrict__ angles) {
  __shared__ float wsh[D_ * 16];   // 64 KB, [d][c]; reads are wave-uniform (broadcast)
  const int tid = threadIdx.x;
  for (int i = tid; i < D_ * 16; i += 128) wsh[i] = Wh[i];
  __syncthreads();
  const int token = blockIdx.x * 128 + tid;     // 0..32767
  const float* xr = x + (size_t)token * D_;
  f32x4 acc4[4];
#pragma unroll
  for (int i = 0; i < 4; i++) acc4[i] = 0.0f;
  for (int d0 = 0; d0 < D_; d0 += 4) {
    const f32x4 pk = *(const f32x4*)(xr + d0);
#pragma unroll
    for (int j = 0; j < 4; j++) {
      const float xv = pk[j];
      const f32x4* wr = (const f32x4*)&wsh[(d0 + j) * 16];
#pragma unroll
      for (int c4 = 0; c4 < 4; c4++) acc4[c4] += wr[c4] * xv;
    }
  }
  const int b = token >> 13, s = token & (S_ - 1);
#pragma unroll
  for (int h = 0; h < H_; h++) {
    const float num = acc4[h >> 1][(h & 1) * 2 + 0];
    const float den = acc4[h >> 1][(h & 1) * 2 + 1];
    angles[(size_t)(b * H_ + h) * S_ + s] = num / (den + 1e-4f);
  }
}

// ---------------- bitonic argsort (ascending) of 8192 angles per (b,h) ----------------
__global__ __launch_bounds__(1024) void sort_k(const float* __restrict__ angles,
                                               int* __restrict__ idx) {
  __shared__ float key[S_];   // 32 KB
  __shared__ int   val[S_];   // 32 KB
  const float* a = angles + (size_t)blockIdx.x * S_;
  const int tid = threadIdx.x;
  for (int i = tid; i < S_; i += 1024) { key[i] = a[i]; val[i] = i; }
  __syncthreads();
  for (int k = 2; k <= S_; k <<= 1) {
    for (int j = k >> 1; j > 0; j >>= 1) {
      for (int i = tid; i < S_; i += 1024) {
        const int ixj = i ^ j;
        if (ixj > i) {
          const float ki = key[i], kj = key[ixj];
          const bool up = (i & k) == 0;
          if (up ? (ki > kj) : (ki < kj)) {
            key[i] = kj; key[ixj] = ki;
            const int t = val[i]; val[i] = val[ixj]; val[ixj] = t;
          }
        }
      }
      __syncthreads();
    }
  }
  int* out = idx + (size_t)blockIdx.x * S_;
  for (int i = tid; i < S_; i += 1024) out[i] = val[i];
}

// ---------------- GEMM: C[M,N] = A[M,K] @ Bt[N,K]^T + bias ----------------
// A,Bt bf16; bias f32; C bf16 or f32 (CF32). 128x128 tile, BK=32,
// global_load_lds width-16 staging (m97 structure), 16x16x32 bf16 MFMA.
template <bool CF32>
__global__ __launch_bounds__(256) void gemm_bt(const u16* __restrict__ A,
                                               const u16* __restrict__ Bt,
                                               const float* __restrict__ bias,
                                               void* __restrict__ Cv,
                                               int M, int N, int K) {
  __shared__ __attribute__((aligned(16))) u16 As[128][32];   // 8 KB, linear (no pad!)
  __shared__ __attribute__((aligned(16))) u16 Bs[128][32];   // 8 KB
  const int tid = threadIdx.x;
  const int wave = tid >> 6, lane = tid & 63;
  const int l16 = lane & 15, quad = lane >> 4;
  const int m0 = blockIdx.x * 128, n0 = blockIdx.y * 128;
  const int wm = wave >> 1, wn = wave & 1;
  // staging geometry: one gload16 per wave covers 16 rows x 32 cols (1 KB);
  // lane l -> row l>>2, col (l&3)*8 u16; LDS dest = wave base + lane*16 B (linear)
  const int srow = lane >> 2;          // 0..15
  const int scol = (lane & 3) * 8;     // u16 col {0,8,16,24}

  const u16* Ag0 = A  + (size_t)(m0 + wave * 16 + srow) * K + scol;
  const u16* Ag1 = A  + (size_t)(m0 + 64 + wave * 16 + srow) * K + scol;
  const u16* Bg0 = Bt + (size_t)(n0 + wave * 16 + srow) * K + scol;
  const u16* Bg1 = Bt + (size_t)(n0 + 64 + wave * 16 + srow) * K + scol;
  u16* AsD0 = &As[wave * 16 + srow][scol];
  u16* AsD1 = &As[64 + wave * 16 + srow][scol];
  u16* BsD0 = &Bs[wave * 16 + srow][scol];
  u16* BsD1 = &Bs[64 + wave * 16 + srow][scol];

  f32x4 acc[4][4];
#pragma unroll
  for (int i = 0; i < 4; i++)
#pragma unroll
    for (int j = 0; j < 4; j++) acc[i][j] = 0.0f;

  for (int k0 = 0; k0 < K; k0 += 32) {
    __syncthreads();   // previous iteration's LDS reads are done
    gload16(Ag0 + k0, AsD0);
    gload16(Ag1 + k0, AsD1);
    gload16(Bg0 + k0, BsD0);
    gload16(Bg1 + k0, BsD1);
    __syncthreads();   // compiler drains vmcnt(0) before s_barrier -> tiles ready
    short8 af[4], bfr[4];
#pragma unroll
    for (int i = 0; i < 4; i++)
      af[i] = *(const short8*)&As[wm * 64 + i * 16 + l16][quad * 8];
#pragma unroll
    for (int i = 0; i < 4; i++)
      bfr[i] = *(const short8*)&Bs[wn * 64 + i * 16 + l16][quad * 8];
#pragma unroll
    for (int mi = 0; mi < 4; mi++)
#pragma unroll
      for (int ni = 0; ni < 4; ni++)
        acc[mi][ni] = mfma16(af[mi], bfr[ni], acc[mi][ni]);
  }

#pragma unroll
  for (int ni = 0; ni < 4; ni++) {
    const int col = n0 + wn * 64 + ni * 16 + l16;
    const float bv = bias[col];
#pragma unroll
    for (int mi = 0; mi < 4; mi++) {
      const int rowb = m0 + wm * 64 + mi * 16 + quad * 4;
#pragma unroll
      for (int r = 0; r < 4; r++) {
        const float cv = acc[mi][ni][r] + bv;
        if (CF32) ((float*)Cv)[(size_t)(rowb + r) * N + col] = cv;
        else      ((u16*)Cv)[(size_t)(rowb + r) * N + col] = f2bf(cv);
      }
    }
  }
}

// ---------------- bucketed attention (shared QK), one block per (b,h,bucket) ----------------
__global__ __launch_bounds__(256) void attn_k(const u16* __restrict__ qbuf,
                                              const u16* __restrict__ vbuf,
                                              const int* __restrict__ idx,
                                              u16* __restrict__ obuf) {
  // LDS strides: odd multiples of 16B -> conflict-free b128, aligned
  __shared__ u16  Qs[64][136];   // 272B stride
  __shared__ u16  Vt[128][72];   // V transposed [dim][token], 144B stride
  __shared__ float Ss[64][65];   // scores; reused as bf16 O staging after softmax
  __shared__ u16  Ps[64][72];
  __shared__ int  tids[64];
  const int b = blockIdx.z, h = blockIdx.y, n = blockIdx.x;
  const int tid = threadIdx.x;
  const int lane = tid & 63, wave = tid >> 6;
  const int l16 = lane & 15, quad = lane >> 4;

  if (tid < 64) tids[tid] = idx[(size_t)(b * H_ + h) * S_ + n * 64 + tid];
  __syncthreads();

  { // gather-load Q (row-major) and V (transposed) head slices
    const int i = tid & 63, seg = tid >> 6;
    const size_t rowoff = (size_t)(b * S_ + tids[i]) * D_ + h * DH_ + seg * 32;
    const u16* qr = qbuf + rowoff;
    const u16* vr = vbuf + rowoff;
#pragma unroll
    for (int c = 0; c < 32; c += 8)
      *(u16x8*)&Qs[i][seg * 32 + c] = *(const u16x8*)(qr + c);
#pragma unroll
    for (int c = 0; c < 32; c += 8) {
      u16x8 pv = *(const u16x8*)(vr + c);
#pragma unroll
      for (int j = 0; j < 8; j++) Vt[seg * 32 + c + j][i] = pv[j];
    }
  }
  __syncthreads();

  // S = Q Q^T * scale ; wave handles score rows [16w,16w+16)
  f32x4 sacc[4];
#pragma unroll
  for (int i = 0; i < 4; i++) sacc[i] = 0.0f;
#pragma unroll
  for (int k0 = 0; k0 < DH_; k0 += 32) {
    const short8 af = *(const short8*)&Qs[wave * 16 + l16][k0 + quad * 8];
#pragma unroll
    for (int ni = 0; ni < 4; ni++) {
      const short8 bfr = *(const short8*)&Qs[ni * 16 + l16][k0 + quad * 8];
      sacc[ni] = mfma16(af, bfr, sacc[ni]);
    }
  }
  const float scale = 0.08838834764831845f;  // 1/sqrt(128)
#pragma unroll
  for (int ni = 0; ni < 4; ni++)
#pragma unroll
    for (int r = 0; r < 4; r++)
      Ss[wave * 16 + quad * 4 + r][ni * 16 + l16] = sacc[ni][r] * scale;
  __syncthreads();

  { // softmax: 4 threads per row (consecutive lanes -> same-wave shuffles)
    const int row = tid >> 2, part = tid & 3;
    float e[16]; float mx = -3.0e38f;
#pragma unroll
    for (int c = 0; c < 16; c++) { e[c] = Ss[row][part * 16 + c]; mx = fmaxf(mx, e[c]); }
    mx = fmaxf(mx, __shfl_xor(mx, 1));
    mx = fmaxf(mx, __shfl_xor(mx, 2));
    float sum = 0.f;
#pragma unroll
    for (int c = 0; c < 16; c++) { e[c] = __expf(e[c] - mx); sum += e[c]; }
    sum += __shfl_xor(sum, 1);
    sum += __shfl_xor(sum, 2);
    const float inv = 1.0f / sum;
#pragma unroll
    for (int c = 0; c < 16; c++) Ps[row][part * 16 + c] = f2bf(e[c] * inv);
  }
  __syncthreads();   // after this barrier Ss is dead -> safe to reuse as Os

  // O = P V ; wave handles O rows [16w,16w+16), 8 dim-tiles
  f32x4 oacc[8];
#pragma unroll
  for (int i = 0; i < 8; i++) oacc[i] = 0.0f;
#pragma unroll
  for (int k0 = 0; k0 < 64; k0 += 32) {
    const short8 pf = *(const short8*)&Ps[wave * 16 + l16][k0 + quad * 8];
#pragma unroll
    for (int nt = 0; nt < 8; nt++) {
      const short8 vf = *(const short8*)&Vt[nt * 16 + l16][k0 + quad * 8];
      oacc[nt] = mfma16(pf, vf, oacc[nt]);
    }
  }

  // stage O in LDS (reuses Ss; 64x128 u16 = 16 KB <= 16.6 KB).
  // column swizzle: col ^ (((m>>2)&3)*32) spreads the 4 quads' rows across
  // 4 distinct 32-col blocks -> conflict-free scalar writes at 256B row stride.
  u16 (*Os)[128] = (u16(*)[128])&Ss[0][0];
#pragma unroll
  for (int r = 0; r < 4; r++) {
    const int m = wave * 16 + quad * 4 + r;
    const int swz = ((m >> 2) & 3) * 32;
#pragma unroll
    for (int nt = 0; nt < 8; nt++) Os[m][(nt * 16 + l16) ^ swz] = f2bf(oacc[nt][r]);
  }
  __syncthreads();

  // coalesced scatter: 4 lanes per row, 64 B each -> one 256 B store per row.
  // (obuf aliases qbuf: this block is the unique reader+writer of its
  //  [tokens x head-slice] region; the Q copy lives in LDS.)
  {
    const int row = tid >> 2, c0 = (tid & 3) * 32;
    const int swz = ((row >> 2) & 3) * 32;
    u16* orow = obuf + (size_t)(b * S_ + tids[row]) * D_ + h * DH_ + c0;
#pragma unroll
    for (int c = 0; c < 32; c += 8)
      *(u16x8*)(orow + c) = *(const u16x8*)&Os[row][(c0 + c) ^ swz];
  }
}

extern "C" void kernel_launch(void* const* d_in, const int* in_sizes, int n_in,
                              void* d_out, int out_size, void* d_ws, size_t ws_size,
                              hipStream_t stream) {
  // ALL inputs are float32 (per the reference file); output is float32.
  const float* x  = (const float*)d_in[0];
  const float* Wh = (const float*)d_in[1];
  const float* Wq = (const float*)d_in[2];
  const float* bq = (const float*)d_in[3];
  const float* Wv = (const float*)d_in[4];
  const float* bv = (const float*)d_in[5];
  const float* Wo = (const float*)d_in[6];
  const float* bo = (const float*)d_in[7];
  char* ws = (char*)d_ws;
  u16*   Wqt    = (u16*)(ws);                    // 2 MiB bf16 [N][K]
  u16*   Wvt    = (u16*)(ws + (2u << 20));       // 2 MiB
  u16*   Wot    = (u16*)(ws + (4u << 20));       // 2 MiB
  float* angles = (float*)(ws + (6u << 20));     // 1 MiB
  int*   idxb   = (int*)(ws + (7u << 20));       // 1 MiB
  u16*   qbuf   = (u16*)(ws + (8u << 20));       // 64 MiB  (ws total: 72 MiB)
  // d_out is 128 MiB of f32; use it as scratch for bf16 x and v until the end
  u16*   xbf    = (u16*)d_out;                           // [0, 64 MiB)
  u16*   vbuf   = (u16*)((char*)d_out + (64u << 20));    // [64, 128 MiB)
  float* out    = (float*)d_out;

  cvt_k<<<dim3(M_ * D_ / (256 * 8), 1, 1), dim3(256, 1, 1), 0, stream>>>(x, xbf);
  transpose_k<<<dim3(32, 32, 1), dim3(32, 8, 1), 0, stream>>>(Wq, Wqt);
  transpose_k<<<dim3(32, 32, 1), dim3(32, 8, 1), 0, stream>>>(Wv, Wvt);
  transpose_k<<<dim3(32, 32, 1), dim3(32, 8, 1), 0, stream>>>(Wo, Wot);
  angles_k<<<dim3(M_ / 128, 1, 1), dim3(128, 1, 1), 0, stream>>>(x, Wh, angles);
  sort_k<<<dim3(B_ * H_, 1, 1), dim3(1024, 1, 1), 0, stream>>>(angles, idxb);
  gemm_bt<false><<<dim3(M_ / 128, D_ / 128, 1), dim3(256, 1, 1), 0, stream>>>(xbf, Wqt, bq, qbuf, M_, D_, D_);
  gemm_bt<false><<<dim3(M_ / 128, D_ / 128, 1), dim3(256, 1, 1), 0, stream>>>(xbf, Wvt, bv, vbuf, M_, D_, D_);
  attn_k<<<dim3(NB_, H_, B_), dim3(256, 1, 1), 0, stream>>>(qbuf, vbuf, idxb, qbuf);
  gemm_bt<true><<<dim3(M_ / 128, D_ / 128, 1), dim3(256, 1, 1), 0, stream>>>(qbuf, Wot, bo, out, M_, D_, D_);
}

// Round 2
// 708.398 us; speedup vs baseline: 1.1633x; 1.1633x over previous
//
#include <hip/hip_runtime.h>

typedef unsigned short u16;
typedef unsigned long long u64;
using short8 = __attribute__((ext_vector_type(8))) short;
using u16x8  = __attribute__((ext_vector_type(8))) unsigned short;
using f32x4  = __attribute__((ext_vector_type(4))) float;

#define B_   4
#define S_   8192
#define D_   1024
#define H_   8
#define DH_  128
#define NB_  128
#define M_   (B_ * S_)   // 32768

static __device__ __forceinline__ float bf2f(u16 u) {
  union { unsigned int i; float f; } v; v.i = ((unsigned int)u) << 16; return v.f;
}
static __device__ __forceinline__ u16 f2bf(float f) {
  unsigned int x = __float_as_uint(f);
  unsigned int r = (x + 0x7fffu + ((x >> 16) & 1u)) >> 16;
  return (u16)r;
}
static __device__ __forceinline__ f32x4 mfma16(short8 a, short8 b, f32x4 c) {
  return __builtin_amdgcn_mfma_f32_16x16x32_bf16(a, b, c, 0, 0, 0);
}
// async global->LDS, 16B per lane; dest MUST be wave-uniform base + lane*16 (linear)
static __device__ __forceinline__ void gload16(const u16* g, u16* l) {
  __builtin_amdgcn_global_load_lds(
      (const __attribute__((address_space(1))) void*)g,
      (__attribute__((address_space(3))) void*)l, 16, 0, 0);
}

// ---------------- convert f32 -> bf16, 8 elems/thread ----------------
__global__ __launch_bounds__(256) void cvt_k(const float* __restrict__ src,
                                             u16* __restrict__ dst) {
  const size_t i = ((size_t)blockIdx.x * 256 + threadIdx.x) * 8;
  const f32x4 a = *(const f32x4*)(src + i);
  const f32x4 b = *(const f32x4*)(src + i + 4);
  u16x8 r;
  r[0] = f2bf(a[0]); r[1] = f2bf(a[1]); r[2] = f2bf(a[2]); r[3] = f2bf(a[3]);
  r[4] = f2bf(b[0]); r[5] = f2bf(b[1]); r[6] = f2bf(b[2]); r[7] = f2bf(b[3]);
  *(u16x8*)(dst + i) = r;
}

// ---------------- transpose 1024x1024: dst_bf16[n][k] = src_f32[k][n] ----------------
__global__ __launch_bounds__(256) void transpose_k(const float* __restrict__ src,
                                                   u16* __restrict__ dst) {
  __shared__ float tile[32][33];
  const int bx = blockIdx.x * 32, by = blockIdx.y * 32;
  const int tx = threadIdx.x, ty = threadIdx.y;
#pragma unroll
  for (int i = ty; i < 32; i += 8) tile[i][tx] = src[(size_t)(by + i) * D_ + bx + tx];
  __syncthreads();
#pragma unroll
  for (int i = ty; i < 32; i += 8) dst[(size_t)(bx + i) * D_ + by + tx] = f2bf(tile[tx][i]);
}

// ---------------- hash keys: key[b][h][s] = ordered(angle)<<32 | s ----------------
// ordered(f) maps f32 total order to u32 order; low 32 bits = token index makes
// every key unique -> any comparison sort reproduces JAX's *stable* argsort.
__global__ __launch_bounds__(128) void keys_k(const float* __restrict__ x,
                                              const float* __restrict__ Wh,
                                              u64* __restrict__ keys) {
  __shared__ float wsh[D_ * 16];   // 64 KB, [d][c]; reads are wave-uniform (broadcast)
  const int tid = threadIdx.x;
  for (int i = tid; i < D_ * 16; i += 128) wsh[i] = Wh[i];
  __syncthreads();
  const int token = blockIdx.x * 128 + tid;     // 0..32767
  const float* xr = x + (size_t)token * D_;
  f32x4 acc4[4];
#pragma unroll
  for (int i = 0; i < 4; i++) acc4[i] = 0.0f;
  for (int d0 = 0; d0 < D_; d0 += 4) {
    const f32x4 pk = *(const f32x4*)(xr + d0);
#pragma unroll
    for (int j = 0; j < 4; j++) {
      const float xv = pk[j];
      const f32x4* wr = (const f32x4*)&wsh[(d0 + j) * 16];
#pragma unroll
      for (int c4 = 0; c4 < 4; c4++) acc4[c4] += wr[c4] * xv;
    }
  }
  const int b = token >> 13, s = token & (S_ - 1);
#pragma unroll
  for (int h = 0; h < H_; h++) {
    const float num = acc4[h >> 1][(h & 1) * 2 + 0];
    const float den = acc4[h >> 1][(h & 1) * 2 + 1];
    const float ang = num / (den + 1e-4f);
    unsigned int ub = __float_as_uint(ang);
    ub = (ub & 0x80000000u) ? ~ub : (ub | 0x80000000u);
    keys[(size_t)(b * H_ + h) * S_ + s] = ((u64)ub << 32) | (unsigned int)s;
  }
}

// ---------------- multi-block bitonic sort of 32 sequences of 8192 u64 keys --------
// Network: for k in 2..8192, j = k/2..1.  Chunk = 2048 elems per block.
// sortA_k: all (k<=2048) phases locally.  sortG_k: one global phase (j>=2048).
// sortB_k: j=1024..1 finisher for given k; FINAL variant extracts idx ints.

__global__ __launch_bounds__(1024) void sortA_k(u64* __restrict__ keys) {
  __shared__ u64 ks[2048];   // 16 KB
  const int seq = blockIdx.y, chunk = blockIdx.x, t = threadIdx.x;
  u64* g = keys + ((size_t)seq << 13) + (chunk << 11);
  ks[t] = g[t]; ks[t + 1024] = g[t + 1024];
  __syncthreads();
  const int gbase = chunk << 11;
  for (int k = 2; k <= 2048; k <<= 1) {
    for (int j = k >> 1; j > 0; j >>= 1) {
      const int i = ((t & ~(j - 1)) << 1) | (t & (j - 1));
      const int p = i | j;
      const bool up = ((gbase + i) & k) == 0;
      const u64 a = ks[i], b = ks[p];
      if ((a > b) == up) { ks[i] = b; ks[p] = a; }
      __syncthreads();
    }
  }
  g[t] = ks[t]; g[t + 1024] = ks[t + 1024];
}

// one global compare-exchange phase (j in {2048,4096}); pair id p grid-wide
__global__ __launch_bounds__(256) void sortG_k(u64* __restrict__ keys, int j, int k) {
  const int p = blockIdx.x * 256 + threadIdx.x;   // 0..131071 (4096 pairs/seq)
  const int seq = p >> 12, q = p & 4095;
  const int i = ((q & ~(j - 1)) << 1) | (q & (j - 1));
  u64* g = keys + ((size_t)seq << 13);
  const bool up = ((i & k) == 0);
  const u64 a = g[i], b = g[i | j];
  if ((a > b) == up) { g[i] = b; g[i | j] = a; }
}

template <int K, bool FINAL>
__global__ __launch_bounds__(1024) void sortB_k(u64* __restrict__ keys,
                                                int* __restrict__ idx) {
  __shared__ u64 ks[2048];
  const int seq = blockIdx.y, chunk = blockIdx.x, t = threadIdx.x;
  u64* g = keys + ((size_t)seq << 13) + (chunk << 11);
  ks[t] = g[t]; ks[t + 1024] = g[t + 1024];
  __syncthreads();
  const int gbase = chunk << 11;
#pragma unroll
  for (int j = 1024; j > 0; j >>= 1) {
    const int i = ((t & ~(j - 1)) << 1) | (t & (j - 1));
    const int p = i | j;
    const bool up = ((gbase + i) & K) == 0;
    const u64 a = ks[i], b = ks[p];
    if ((a > b) == up) { ks[i] = b; ks[p] = a; }
    __syncthreads();
  }
  if (FINAL) {
    int* o = idx + ((size_t)seq << 13) + (chunk << 11);
    o[t] = (int)(unsigned int)ks[t];
    o[t + 1024] = (int)(unsigned int)ks[t + 1024];
  } else {
    g[t] = ks[t]; g[t + 1024] = ks[t + 1024];
  }
}

// ---------------- GEMM: C[M,N] = A[M,K] @ Bt[N,K]^T + bias ----------------
// A,Bt bf16; bias f32; C bf16 or f32 (CF32). 128x128 tile, BK=32,
// global_load_lds width-16 staging (m97 structure), 16x16x32 bf16 MFMA.
template <bool CF32>
__global__ __launch_bounds__(256) void gemm_bt(const u16* __restrict__ A,
                                               const u16* __restrict__ Bt,
                                               const float* __restrict__ bias,
                                               void* __restrict__ Cv,
                                               int M, int N, int K) {
  __shared__ __attribute__((aligned(16))) u16 As[128][32];   // 8 KB, linear (no pad!)
  __shared__ __attribute__((aligned(16))) u16 Bs[128][32];   // 8 KB
  const int tid = threadIdx.x;
  const int wave = tid >> 6, lane = tid & 63;
  const int l16 = lane & 15, quad = lane >> 4;
  const int m0 = blockIdx.x * 128, n0 = blockIdx.y * 128;
  const int wm = wave >> 1, wn = wave & 1;
  // staging geometry: one gload16 per wave covers 16 rows x 32 cols (1 KB);
  // lane l -> row l>>2, col (l&3)*8 u16; LDS dest = wave base + lane*16 B (linear)
  const int srow = lane >> 2;          // 0..15
  const int scol = (lane & 3) * 8;     // u16 col {0,8,16,24}

  const u16* Ag0 = A  + (size_t)(m0 + wave * 16 + srow) * K + scol;
  const u16* Ag1 = A  + (size_t)(m0 + 64 + wave * 16 + srow) * K + scol;
  const u16* Bg0 = Bt + (size_t)(n0 + wave * 16 + srow) * K + scol;
  const u16* Bg1 = Bt + (size_t)(n0 + 64 + wave * 16 + srow) * K + scol;
  u16* AsD0 = &As[wave * 16 + srow][scol];
  u16* AsD1 = &As[64 + wave * 16 + srow][scol];
  u16* BsD0 = &Bs[wave * 16 + srow][scol];
  u16* BsD1 = &Bs[64 + wave * 16 + srow][scol];

  f32x4 acc[4][4];
#pragma unroll
  for (int i = 0; i < 4; i++)
#pragma unroll
    for (int j = 0; j < 4; j++) acc[i][j] = 0.0f;

  for (int k0 = 0; k0 < K; k0 += 32) {
    __syncthreads();   // previous iteration's LDS reads are done
    gload16(Ag0 + k0, AsD0);
    gload16(Ag1 + k0, AsD1);
    gload16(Bg0 + k0, BsD0);
    gload16(Bg1 + k0, BsD1);
    __syncthreads();   // compiler drains vmcnt(0) before s_barrier -> tiles ready
    short8 af[4], bfr[4];
#pragma unroll
    for (int i = 0; i < 4; i++)
      af[i] = *(const short8*)&As[wm * 64 + i * 16 + l16][quad * 8];
#pragma unroll
    for (int i = 0; i < 4; i++)
      bfr[i] = *(const short8*)&Bs[wn * 64 + i * 16 + l16][quad * 8];
#pragma unroll
    for (int mi = 0; mi < 4; mi++)
#pragma unroll
      for (int ni = 0; ni < 4; ni++)
        acc[mi][ni] = mfma16(af[mi], bfr[ni], acc[mi][ni]);
  }

#pragma unroll
  for (int ni = 0; ni < 4; ni++) {
    const int col = n0 + wn * 64 + ni * 16 + l16;
    const float bv = bias[col];
#pragma unroll
    for (int mi = 0; mi < 4; mi++) {
      const int rowb = m0 + wm * 64 + mi * 16 + quad * 4;
#pragma unroll
      for (int r = 0; r < 4; r++) {
        const float cv = acc[mi][ni][r] + bv;
        if (CF32) ((float*)Cv)[(size_t)(rowb + r) * N + col] = cv;
        else      ((u16*)Cv)[(size_t)(rowb + r) * N + col] = f2bf(cv);
      }
    }
  }
}

// ---------------- bucketed attention (shared QK), one block per (b,h,bucket) ----------------
__global__ __launch_bounds__(256) void attn_k(const u16* __restrict__ qbuf,
                                              const u16* __restrict__ vbuf,
                                              const int* __restrict__ idx,
                                              u16* __restrict__ obuf) {
  // LDS strides: odd multiples of 16B -> conflict-free b128, aligned
  __shared__ u16  Qs[64][136];   // 272B stride
  __shared__ u16  Vt[128][72];   // V transposed [dim][token], 144B stride
  __shared__ float Ss[64][65];   // scores; reused as bf16 O staging after softmax
  __shared__ u16  Ps[64][72];
  __shared__ int  tids[64];
  const int b = blockIdx.z, h = blockIdx.y, n = blockIdx.x;
  const int tid = threadIdx.x;
  const int lane = tid & 63, wave = tid >> 6;
  const int l16 = lane & 15, quad = lane >> 4;

  if (tid < 64) tids[tid] = idx[(size_t)(b * H_ + h) * S_ + n * 64 + tid];
  __syncthreads();

  { // gather-load Q (row-major) and V (transposed) head slices
    const int i = tid & 63, seg = tid >> 6;
    const size_t rowoff = (size_t)(b * S_ + tids[i]) * D_ + h * DH_ + seg * 32;
    const u16* qr = qbuf + rowoff;
    const u16* vr = vbuf + rowoff;
#pragma unroll
    for (int c = 0; c < 32; c += 8)
      *(u16x8*)&Qs[i][seg * 32 + c] = *(const u16x8*)(qr + c);
#pragma unroll
    for (int c = 0; c < 32; c += 8) {
      u16x8 pv = *(const u16x8*)(vr + c);
#pragma unroll
      for (int j = 0; j < 8; j++) Vt[seg * 32 + c + j][i] = pv[j];
    }
  }
  __syncthreads();

  // S = Q Q^T * scale ; wave handles score rows [16w,16w+16)
  f32x4 sacc[4];
#pragma unroll
  for (int i = 0; i < 4; i++) sacc[i] = 0.0f;
#pragma unroll
  for (int k0 = 0; k0 < DH_; k0 += 32) {
    const short8 af = *(const short8*)&Qs[wave * 16 + l16][k0 + quad * 8];
#pragma unroll
    for (int ni = 0; ni < 4; ni++) {
      const short8 bfr = *(const short8*)&Qs[ni * 16 + l16][k0 + quad * 8];
      sacc[ni] = mfma16(af, bfr, sacc[ni]);
    }
  }
  const float scale = 0.08838834764831845f;  // 1/sqrt(128)
#pragma unroll
  for (int ni = 0; ni < 4; ni++)
#pragma unroll
    for (int r = 0; r < 4; r++)
      Ss[wave * 16 + quad * 4 + r][ni * 16 + l16] = sacc[ni][r] * scale;
  __syncthreads();

  { // softmax: 4 threads per row (consecutive lanes -> same-wave shuffles)
    const int row = tid >> 2, part = tid & 3;
    float e[16]; float mx = -3.0e38f;
#pragma unroll
    for (int c = 0; c < 16; c++) { e[c] = Ss[row][part * 16 + c]; mx = fmaxf(mx, e[c]); }
    mx = fmaxf(mx, __shfl_xor(mx, 1));
    mx = fmaxf(mx, __shfl_xor(mx, 2));
    float sum = 0.f;
#pragma unroll
    for (int c = 0; c < 16; c++) { e[c] = __expf(e[c] - mx); sum += e[c]; }
    sum += __shfl_xor(sum, 1);
    sum += __shfl_xor(sum, 2);
    const float inv = 1.0f / sum;
#pragma unroll
    for (int c = 0; c < 16; c++) Ps[row][part * 16 + c] = f2bf(e[c] * inv);
  }
  __syncthreads();   // after this barrier Ss is dead -> safe to reuse as Os

  // O = P V ; wave handles O rows [16w,16w+16), 8 dim-tiles
  f32x4 oacc[8];
#pragma unroll
  for (int i = 0; i < 8; i++) oacc[i] = 0.0f;
#pragma unroll
  for (int k0 = 0; k0 < 64; k0 += 32) {
    const short8 pf = *(const short8*)&Ps[wave * 16 + l16][k0 + quad * 8];
#pragma unroll
    for (int nt = 0; nt < 8; nt++) {
      const short8 vf = *(const short8*)&Vt[nt * 16 + l16][k0 + quad * 8];
      oacc[nt] = mfma16(pf, vf, oacc[nt]);
    }
  }

  // stage O in LDS (reuses Ss; 64x128 u16 = 16 KB <= 16.6 KB).
  // column swizzle: col ^ (((m>>2)&3)*32) spreads the 4 quads' rows across
  // 4 distinct 32-col blocks -> conflict-free scalar writes at 256B row stride.
  u16 (*Os)[128] = (u16(*)[128])&Ss[0][0];
#pragma unroll
  for (int r = 0; r < 4; r++) {
    const int m = wave * 16 + quad * 4 + r;
    const int swz = ((m >> 2) & 3) * 32;
#pragma unroll
    for (int nt = 0; nt < 8; nt++) Os[m][(nt * 16 + l16) ^ swz] = f2bf(oacc[nt][r]);
  }
  __syncthreads();

  // coalesced scatter: 4 lanes per row, 64 B each -> one 256 B store per row.
  // (obuf aliases qbuf: this block is the unique reader+writer of its
  //  [tokens x head-slice] region; the Q copy lives in LDS.)
  {
    const int row = tid >> 2, c0 = (tid & 3) * 32;
    const int swz = ((row >> 2) & 3) * 32;
    u16* orow = obuf + (size_t)(b * S_ + tids[row]) * D_ + h * DH_ + c0;
#pragma unroll
    for (int c = 0; c < 32; c += 8)
      *(u16x8*)(orow + c) = *(const u16x8*)&Os[row][(c0 + c) ^ swz];
  }
}

extern "C" void kernel_launch(void* const* d_in, const int* in_sizes, int n_in,
                              void* d_out, int out_size, void* d_ws, size_t ws_size,
                              hipStream_t stream) {
  // ALL inputs are float32 (per the reference file); output is float32.
  const float* x  = (const float*)d_in[0];
  const float* Wh = (const float*)d_in[1];
  const float* Wq = (const float*)d_in[2];
  const float* bq = (const float*)d_in[3];
  const float* Wv = (const float*)d_in[4];
  const float* bv = (const float*)d_in[5];
  const float* Wo = (const float*)d_in[6];
  const float* bo = (const float*)d_in[7];
  char* ws = (char*)d_ws;
  u16*   Wqt    = (u16*)(ws);                    // 2 MiB bf16 [N][K]
  u16*   Wvt    = (u16*)(ws + (2u << 20));       // 2 MiB
  u16*   Wot    = (u16*)(ws + (4u << 20));       // 2 MiB
  int*   idxb   = (int*)(ws + (7u << 20));       // 1 MiB
  u16*   qbuf   = (u16*)(ws + (8u << 20));       // 64 MiB  (ws total: 72 MiB)
  // d_out is 128 MiB of f32; use it as scratch until the end:
  u16*   xbf    = (u16*)d_out;                           // [0, 64 MiB)  bf16 x
  u16*   vbuf   = (u16*)((char*)d_out + (64u << 20));    // [64, 128 MiB) bf16 v
  // sort keys (2 MiB) borrow the head of vbuf's region: dead before gemm_v writes
  u64*   keys   = (u64*)((char*)d_out + (64u << 20));
  float* out    = (float*)d_out;

  cvt_k<<<dim3(M_ * D_ / (256 * 8), 1, 1), dim3(256, 1, 1), 0, stream>>>(x, xbf);
  transpose_k<<<dim3(32, 32, 1), dim3(32, 8, 1), 0, stream>>>(Wq, Wqt);
  transpose_k<<<dim3(32, 32, 1), dim3(32, 8, 1), 0, stream>>>(Wv, Wvt);
  transpose_k<<<dim3(32, 32, 1), dim3(32, 8, 1), 0, stream>>>(Wo, Wot);
  keys_k<<<dim3(M_ / 128, 1, 1), dim3(128, 1, 1), 0, stream>>>(x, Wh, keys);
  // multi-block bitonic: k<=2048 local, then (k=4096, k=8192) global+local finishers
  sortA_k<<<dim3(4, 32, 1), dim3(1024, 1, 1), 0, stream>>>(keys);
  sortG_k<<<dim3(512, 1, 1), dim3(256, 1, 1), 0, stream>>>(keys, 2048, 4096);
  sortB_k<4096, false><<<dim3(4, 32, 1), dim3(1024, 1, 1), 0, stream>>>(keys, idxb);
  sortG_k<<<dim3(512, 1, 1), dim3(256, 1, 1), 0, stream>>>(keys, 4096, 8192);
  sortG_k<<<dim3(512, 1, 1), dim3(256, 1, 1), 0, stream>>>(keys, 2048, 8192);
  sortB_k<8192, true><<<dim3(4, 32, 1), dim3(1024, 1, 1), 0, stream>>>(keys, idxb);
  gemm_bt<false><<<dim3(M_ / 128, D_ / 128, 1), dim3(256, 1, 1), 0, stream>>>(xbf, Wqt, bq, qbuf, M_, D_, D_);
  gemm_bt<false><<<dim3(M_ / 128, D_ / 128, 1), dim3(256, 1, 1), 0, stream>>>(xbf, Wvt, bv, vbuf, M_, D_, D_);
  attn_k<<<dim3(NB_, H_, B_), dim3(256, 1, 1), 0, stream>>>(qbuf, vbuf, idxb, qbuf);
  gemm_bt<true><<<dim3(M_ / 128, D_ / 128, 1), dim3(256, 1, 1), 0, stream>>>(qbuf, Wot, bo, out, M_, D_, D_);
}

// Round 4
// 675.902 us; speedup vs baseline: 1.2192x; 1.0481x over previous
//
#include <hip/hip_runtime.h>

typedef unsigned short u16;
typedef unsigned long long u64;
using short8 = __attribute__((ext_vector_type(8))) short;
using u16x8  = __attribute__((ext_vector_type(8))) unsigned short;
using f32x4  = __attribute__((ext_vector_type(4))) float;

#define B_   4
#define S_   8192
#define D_   1024
#define H_   8
#define DH_  128
#define NB_  128
#define M_   (B_ * S_)   // 32768

static __device__ __forceinline__ float bf2f(u16 u) {
  union { unsigned int i; float f; } v; v.i = ((unsigned int)u) << 16; return v.f;
}
static __device__ __forceinline__ u16 f2bf(float f) {
  unsigned int x = __float_as_uint(f);
  unsigned int r = (x + 0x7fffu + ((x >> 16) & 1u)) >> 16;
  return (u16)r;
}
static __device__ __forceinline__ f32x4 mfma16(short8 a, short8 b, f32x4 c) {
  return __builtin_amdgcn_mfma_f32_16x16x32_bf16(a, b, c, 0, 0, 0);
}
// async global->LDS, 16B per lane; dest MUST be wave-uniform base + lane*16 (linear)
static __device__ __forceinline__ void gload16(const u16* g, u16* l) {
  __builtin_amdgcn_global_load_lds(
      (const __attribute__((address_space(1))) void*)g,
      (__attribute__((address_space(3))) void*)l, 16, 0, 0);
}

// ---------------- convert f32 -> bf16, 8 elems/thread ----------------
__global__ __launch_bounds__(256) void cvt_k(const float* __restrict__ src,
                                             u16* __restrict__ dst) {
  const size_t i = ((size_t)blockIdx.x * 256 + threadIdx.x) * 8;
  const f32x4 a = *(const f32x4*)(src + i);
  const f32x4 b = *(const f32x4*)(src + i + 4);
  u16x8 r;
  r[0] = f2bf(a[0]); r[1] = f2bf(a[1]); r[2] = f2bf(a[2]); r[3] = f2bf(a[3]);
  r[4] = f2bf(b[0]); r[5] = f2bf(b[1]); r[6] = f2bf(b[2]); r[7] = f2bf(b[3]);
  *(u16x8*)(dst + i) = r;
}

// ---------------- transpose 1024x1024: dst_bf16[n][k] = src_f32[k][n] ----------------
__global__ __launch_bounds__(256) void transpose_k(const float* __restrict__ src,
                                                   u16* __restrict__ dst) {
  __shared__ float tile[32][33];
  const int bx = blockIdx.x * 32, by = blockIdx.y * 32;
  const int tx = threadIdx.x, ty = threadIdx.y;
#pragma unroll
  for (int i = ty; i < 32; i += 8) tile[i][tx] = src[(size_t)(by + i) * D_ + bx + tx];
  __syncthreads();
#pragma unroll
  for (int i = ty; i < 32; i += 8) dst[(size_t)(bx + i) * D_ + by + tx] = f2bf(tile[tx][i]);
}

// ---------------- hash keys: key[b][h][s] = ordered(angle)<<32 | s ----------------
__global__ __launch_bounds__(128) void keys_k(const float* __restrict__ x,
                                              const float* __restrict__ Wh,
                                              u64* __restrict__ keys) {
  __shared__ float wsh[D_ * 16];   // 64 KB
  const int tid = threadIdx.x;
  for (int i = tid; i < D_ * 16; i += 128) wsh[i] = Wh[i];
  __syncthreads();
  const int token = blockIdx.x * 128 + tid;     // 0..32767
  const float* xr = x + (size_t)token * D_;
  f32x4 acc4[4];
#pragma unroll
  for (int i = 0; i < 4; i++) acc4[i] = 0.0f;
  for (int d0 = 0; d0 < D_; d0 += 4) {
    const f32x4 pk = *(const f32x4*)(xr + d0);
#pragma unroll
    for (int j = 0; j < 4; j++) {
      const float xv = pk[j];
      const f32x4* wr = (const f32x4*)&wsh[(d0 + j) * 16];
#pragma unroll
      for (int c4 = 0; c4 < 4; c4++) acc4[c4] += wr[c4] * xv;
    }
  }
  const int b = token >> 13, s = token & (S_ - 1);
#pragma unroll
  for (int h = 0; h < H_; h++) {
    const float num = acc4[h >> 1][(h & 1) * 2 + 0];
    const float den = acc4[h >> 1][(h & 1) * 2 + 1];
    const float ang = num / (den + 1e-4f);
    unsigned int ub = __float_as_uint(ang);
    ub = (ub & 0x80000000u) ? ~ub : (ub | 0x80000000u);
    keys[(size_t)(b * H_ + h) * S_ + s] = ((u64)ub << 32) | (unsigned int)s;
  }
}

// ---------------- multi-block bitonic sort of 32 sequences of 8192 u64 keys --------
__global__ __launch_bounds__(1024) void sortA_k(u64* __restrict__ keys) {
  __shared__ u64 ks[2048];   // 16 KB
  const int seq = blockIdx.y, chunk = blockIdx.x, t = threadIdx.x;
  u64* g = keys + ((size_t)seq << 13) + (chunk << 11);
  ks[t] = g[t]; ks[t + 1024] = g[t + 1024];
  __syncthreads();
  const int gbase = chunk << 11;
  for (int k = 2; k <= 2048; k <<= 1) {
    for (int j = k >> 1; j > 0; j >>= 1) {
      const int i = ((t & ~(j - 1)) << 1) | (t & (j - 1));
      const int p = i | j;
      const bool up = ((gbase + i) & k) == 0;
      const u64 a = ks[i], b = ks[p];
      if ((a > b) == up) { ks[i] = b; ks[p] = a; }
      __syncthreads();
    }
  }
  g[t] = ks[t]; g[t + 1024] = ks[t + 1024];
}

__global__ __launch_bounds__(256) void sortG_k(u64* __restrict__ keys, int j, int k) {
  const int p = blockIdx.x * 256 + threadIdx.x;   // 4096 pairs/seq
  const int seq = p >> 12, q = p & 4095;
  const int i = ((q & ~(j - 1)) << 1) | (q & (j - 1));
  u64* g = keys + ((size_t)seq << 13);
  const bool up = ((i & k) == 0);
  const u64 a = g[i], b = g[i | j];
  if ((a > b) == up) { g[i] = b; g[i | j] = a; }
}

template <int K, bool FINAL>
__global__ __launch_bounds__(1024) void sortB_k(u64* __restrict__ keys,
                                                int* __restrict__ idx) {
  __shared__ u64 ks[2048];
  const int seq = blockIdx.y, chunk = blockIdx.x, t = threadIdx.x;
  u64* g = keys + ((size_t)seq << 13) + (chunk << 11);
  ks[t] = g[t]; ks[t + 1024] = g[t + 1024];
  __syncthreads();
  const int gbase = chunk << 11;
#pragma unroll
  for (int j = 1024; j > 0; j >>= 1) {
    const int i = ((t & ~(j - 1)) << 1) | (t & (j - 1));
    const int p = i | j;
    const bool up = ((gbase + i) & K) == 0;
    const u64 a = ks[i], b = ks[p];
    if ((a > b) == up) { ks[i] = b; ks[p] = a; }
    __syncthreads();
  }
  if (FINAL) {
    int* o = idx + ((size_t)seq << 13) + (chunk << 11);
    o[t] = (int)(unsigned int)ks[t];
    o[t + 1024] = (int)(unsigned int)ks[t + 1024];
  } else {
    g[t] = ks[t]; g[t + 1024] = ks[t + 1024];
  }
}

// ---------------- GEMM: C[M,N] = A[M,K] @ Bt[N,K]^T + bias ----------------
// 256x256 tile, BK=64, 8 waves (2x4). SINGLE-buffered LDS staging with the
// R2-proven two-barrier flow: [barrier] stage(gload_lds x8) [barrier] compute.
// XOR swizzle: LDS[r][slot s] = G[r][s ^ (r&7)] via pre-swizzled global source
// (linear LDS dest, as gload_lds requires); reads apply the same XOR.
template <bool CF32>
__global__ __launch_bounds__(512, 2) void gemm_bt(const u16* __restrict__ A,
                                                  const u16* __restrict__ Bt,
                                                  const float* __restrict__ bias,
                                                  void* __restrict__ Cv,
                                                  int M, int N, int K) {
  // staging uses first 32768 u16 (A: [0,16384), B: [16384,32768));
  // full 65536 u16 (128 KB) reused as the C staging tile in the bf16 epilogue.
  __shared__ __attribute__((aligned(16))) u16 lds[65536];
  const int tid = threadIdx.x;
  const int wave = tid >> 6, lane = tid & 63;
  const int l16 = lane & 15, quad = lane >> 4;
  const int wm = wave >> 2, wn = wave & 3;       // 2 x 4 wave grid
  const int m0 = blockIdx.x * 256, n0 = blockIdx.y * 256;

  // staging: thread -> row rl=tid>>3 (of each 64-row round), slot ss=tid&7.
  // LDS dest linear (tid*16B); global col pre-swizzled by the row's XOR.
  const int rl = tid >> 3, ss = tid & 7;
  const int scol = ((ss ^ (rl & 7)) << 3);
  const u16* Ag = A  + (size_t)(m0 + rl) * K + scol;
  const u16* Bg = Bt + (size_t)(n0 + rl) * K + scol;

  f32x4 acc[8][4];
#pragma unroll
  for (int i = 0; i < 8; i++)
#pragma unroll
    for (int j = 0; j < 4; j++) acc[i][j] = 0.0f;

  const int NT = K >> 6;      // 16 for K=1024
  for (int t = 0; t < NT; ++t) {
    __syncthreads();          // previous iteration's LDS reads are done
    {
      const size_t k0s = (size_t)t * 64;
      u16* ad = lds + tid * 8;
      u16* bd = lds + 16384 + tid * 8;
#pragma unroll
      for (int j = 0; j < 4; ++j) {
        gload16(Ag + (size_t)(64 * j) * K + k0s, ad + j * 4096);
        gload16(Bg + (size_t)(64 * j) * K + k0s, bd + j * 4096);
      }
    }
    __syncthreads();          // vmcnt drained before barrier -> tile ready
    const u16* Ab = lds;
    const u16* Bb = lds + 16384;
#pragma unroll
    for (int kh = 0; kh < 2; ++kh) {
      short8 a[8], b[4];
#pragma unroll
      for (int mi = 0; mi < 8; ++mi) {
        const int r = wm * 128 + mi * 16 + l16;
        a[mi] = *(const short8*)(Ab + r * 64 + (((kh * 4 + quad) ^ (r & 7)) << 3));
      }
#pragma unroll
      for (int ni = 0; ni < 4; ++ni) {
        const int r = wn * 64 + ni * 16 + l16;
        b[ni] = *(const short8*)(Bb + r * 64 + (((kh * 4 + quad) ^ (r & 7)) << 3));
      }
#pragma unroll
      for (int mi = 0; mi < 8; ++mi)
#pragma unroll
        for (int ni = 0; ni < 4; ++ni)
          acc[mi][ni] = mfma16(a[mi], b[ni], acc[mi][ni]);
    }
  }
  __syncthreads();            // all LDS reads done before epilogue reuse

  if (CF32) {
#pragma unroll
    for (int ni = 0; ni < 4; ++ni) {
      const int col = n0 + wn * 64 + ni * 16 + l16;
      const float bv = bias[col];
#pragma unroll
      for (int mi = 0; mi < 8; ++mi) {
        const int rowb = m0 + wm * 128 + mi * 16 + quad * 4;
#pragma unroll
        for (int r = 0; r < 4; ++r)
          ((float*)Cv)[(size_t)(rowb + r) * N + col] = acc[mi][ni][r] + bv;
      }
    }
  } else {
    // stage C tile in LDS for coalesced 16B stores
    u16* Cs = lds;   // [256][256] u16 = 128 KB
#pragma unroll
    for (int ni = 0; ni < 4; ++ni) {
      const int col = wn * 64 + ni * 16 + l16;
      const float bv = bias[n0 + col];
#pragma unroll
      for (int mi = 0; mi < 8; ++mi) {
#pragma unroll
        for (int r = 0; r < 4; ++r) {
          const int row = wm * 128 + mi * 16 + quad * 4 + r;
          Cs[row * 256 + col] = f2bf(acc[mi][ni][r] + bv);
        }
      }
    }
    __syncthreads();
    u16* Cg = (u16*)Cv;
    const int rrow = tid >> 5, sl = tid & 31;   // 32 x 16B slots = one 512B row
#pragma unroll
    for (int pass = 0; pass < 16; ++pass) {
      const int row = pass * 16 + rrow;
      *(u16x8*)(Cg + (size_t)(m0 + row) * N + n0 + sl * 8) =
          *(const u16x8*)(Cs + row * 256 + sl * 8);
    }
  }
}

// ---------------- bucketed attention (shared QK), one block per (b,h,bucket) ----------------
__global__ __launch_bounds__(256) void attn_k(const u16* __restrict__ qbuf,
                                              const u16* __restrict__ vbuf,
                                              const int* __restrict__ idx,
                                              u16* __restrict__ obuf) {
  __shared__ u16  Qs[64][136];   // 272B stride
  __shared__ u16  Vt[128][72];   // V transposed [dim][token], 144B stride
  __shared__ float Ss[64][65];   // scores; reused as bf16 O staging after softmax
  __shared__ u16  Ps[64][72];
  __shared__ int  tids[64];
  const int b = blockIdx.z, h = blockIdx.y, n = blockIdx.x;
  const int tid = threadIdx.x;
  const int lane = tid & 63, wave = tid >> 6;
  const int l16 = lane & 15, quad = lane >> 4;

  if (tid < 64) tids[tid] = idx[(size_t)(b * H_ + h) * S_ + n * 64 + tid];
  __syncthreads();

  { // gather-load Q (row-major) and V (transposed) head slices
    const int i = tid & 63, seg = tid >> 6;
    const size_t rowoff = (size_t)(b * S_ + tids[i]) * D_ + h * DH_ + seg * 32;
    const u16* qr = qbuf + rowoff;
    const u16* vr = vbuf + rowoff;
#pragma unroll
    for (int c = 0; c < 32; c += 8)
      *(u16x8*)&Qs[i][seg * 32 + c] = *(const u16x8*)(qr + c);
#pragma unroll
    for (int c = 0; c < 32; c += 8) {
      u16x8 pv = *(const u16x8*)(vr + c);
#pragma unroll
      for (int j = 0; j < 8; j++) Vt[seg * 32 + c + j][i] = pv[j];
    }
  }
  __syncthreads();

  // S = Q Q^T * scale
  f32x4 sacc[4];
#pragma unroll
  for (int i = 0; i < 4; i++) sacc[i] = 0.0f;
#pragma unroll
  for (int k0 = 0; k0 < DH_; k0 += 32) {
    const short8 af = *(const short8*)&Qs[wave * 16 + l16][k0 + quad * 8];
#pragma unroll
    for (int ni = 0; ni < 4; ni++) {
      const short8 bfr = *(const short8*)&Qs[ni * 16 + l16][k0 + quad * 8];
      sacc[ni] = mfma16(af, bfr, sacc[ni]);
    }
  }
  const float scale = 0.08838834764831845f;  // 1/sqrt(128)
#pragma unroll
  for (int ni = 0; ni < 4; ni++)
#pragma unroll
    for (int r = 0; r < 4; r++)
      Ss[wave * 16 + quad * 4 + r][ni * 16 + l16] = sacc[ni][r] * scale;
  __syncthreads();

  { // softmax: 4 threads per row
    const int row = tid >> 2, part = tid & 3;
    float e[16]; float mx = -3.0e38f;
#pragma unroll
    for (int c = 0; c < 16; c++) { e[c] = Ss[row][part * 16 + c]; mx = fmaxf(mx, e[c]); }
    mx = fmaxf(mx, __shfl_xor(mx, 1));
    mx = fmaxf(mx, __shfl_xor(mx, 2));
    float sum = 0.f;
#pragma unroll
    for (int c = 0; c < 16; c++) { e[c] = __expf(e[c] - mx); sum += e[c]; }
    sum += __shfl_xor(sum, 1);
    sum += __shfl_xor(sum, 2);
    const float inv = 1.0f / sum;
#pragma unroll
    for (int c = 0; c < 16; c++) Ps[row][part * 16 + c] = f2bf(e[c] * inv);
  }
  __syncthreads();   // Ss dead -> reuse as Os

  // O = P V
  f32x4 oacc[8];
#pragma unroll
  for (int i = 0; i < 8; i++) oacc[i] = 0.0f;
#pragma unroll
  for (int k0 = 0; k0 < 64; k0 += 32) {
    const short8 pf = *(const short8*)&Ps[wave * 16 + l16][k0 + quad * 8];
#pragma unroll
    for (int nt = 0; nt < 8; nt++) {
      const short8 vf = *(const short8*)&Vt[nt * 16 + l16][k0 + quad * 8];
      oacc[nt] = mfma16(pf, vf, oacc[nt]);
    }
  }

  u16 (*Os)[128] = (u16(*)[128])&Ss[0][0];
#pragma unroll
  for (int r = 0; r < 4; r++) {
    const int m = wave * 16 + quad * 4 + r;
    const int swz = ((m >> 2) & 3) * 32;
#pragma unroll
    for (int nt = 0; nt < 8; nt++) Os[m][(nt * 16 + l16) ^ swz] = f2bf(oacc[nt][r]);
  }
  __syncthreads();

  { // coalesced scatter
    const int row = tid >> 2, c0 = (tid & 3) * 32;
    const int swz = ((row >> 2) & 3) * 32;
    u16* orow = obuf + (size_t)(b * S_ + tids[row]) * D_ + h * DH_ + c0;
#pragma unroll
    for (int c = 0; c < 32; c += 8)
      *(u16x8*)(orow + c) = *(const u16x8*)&Os[row][(c0 + c) ^ swz];
  }
}

extern "C" void kernel_launch(void* const* d_in, const int* in_sizes, int n_in,
                              void* d_out, int out_size, void* d_ws, size_t ws_size,
                              hipStream_t stream) {
  const float* x  = (const float*)d_in[0];
  const float* Wh = (const float*)d_in[1];
  const float* Wq = (const float*)d_in[2];
  const float* bq = (const float*)d_in[3];
  const float* Wv = (const float*)d_in[4];
  const float* bv = (const float*)d_in[5];
  const float* Wo = (const float*)d_in[6];
  const float* bo = (const float*)d_in[7];
  char* ws = (char*)d_ws;
  u16*   Wqt    = (u16*)(ws);                    // 2 MiB bf16 [N][K]
  u16*   Wvt    = (u16*)(ws + (2u << 20));       // 2 MiB
  u16*   Wot    = (u16*)(ws + (4u << 20));       // 2 MiB
  int*   idxb   = (int*)(ws + (7u << 20));       // 1 MiB
  u16*   qbuf   = (u16*)(ws + (8u << 20));       // 64 MiB
  u16*   xbf    = (u16*)d_out;                           // [0, 64 MiB)  bf16 x
  u16*   vbuf   = (u16*)((char*)d_out + (64u << 20));    // [64, 128 MiB) bf16 v
  u64*   keys   = (u64*)((char*)d_out + (64u << 20));    // 2 MiB, dead before gemm_v
  float* out    = (float*)d_out;

  cvt_k<<<dim3(M_ * D_ / (256 * 8), 1, 1), dim3(256, 1, 1), 0, stream>>>(x, xbf);
  transpose_k<<<dim3(32, 32, 1), dim3(32, 8, 1), 0, stream>>>(Wq, Wqt);
  transpose_k<<<dim3(32, 32, 1), dim3(32, 8, 1), 0, stream>>>(Wv, Wvt);
  transpose_k<<<dim3(32, 32, 1), dim3(32, 8, 1), 0, stream>>>(Wo, Wot);
  keys_k<<<dim3(M_ / 128, 1, 1), dim3(128, 1, 1), 0, stream>>>(x, Wh, keys);
  sortA_k<<<dim3(4, 32, 1), dim3(1024, 1, 1), 0, stream>>>(keys);
  sortG_k<<<dim3(512, 1, 1), dim3(256, 1, 1), 0, stream>>>(keys, 2048, 4096);
  sortB_k<4096, false><<<dim3(4, 32, 1), dim3(1024, 1, 1), 0, stream>>>(keys, idxb);
  sortG_k<<<dim3(512, 1, 1), dim3(256, 1, 1), 0, stream>>>(keys, 4096, 8192);
  sortG_k<<<dim3(512, 1, 1), dim3(256, 1, 1), 0, stream>>>(keys, 2048, 8192);
  sortB_k<8192, true><<<dim3(4, 32, 1), dim3(1024, 1, 1), 0, stream>>>(keys, idxb);
  gemm_bt<false><<<dim3(M_ / 256, D_ / 256, 1), dim3(512, 1, 1), 0, stream>>>(xbf, Wqt, bq, qbuf, M_, D_, D_);
  gemm_bt<false><<<dim3(M_ / 256, D_ / 256, 1), dim3(512, 1, 1), 0, stream>>>(xbf, Wvt, bv, vbuf, M_, D_, D_);
  attn_k<<<dim3(NB_, H_, B_), dim3(256, 1, 1), 0, stream>>>(qbuf, vbuf, idxb, qbuf);
  gemm_bt<true><<<dim3(M_ / 256, D_ / 256, 1), dim3(512, 1, 1), 0, stream>>>(qbuf, Wot, bo, out, M_, D_, D_);
}